// Round 5
// baseline (703.309 us; speedup 1.0000x reference)
//
#include <hip/hip_runtime.h>
#include <hip/hip_bf16.h>
#include <math.h>

#define NB 4
#define NN 4096
#define NC 128
#define NH 8
#define NV 16
#define BD 64   // NB*NV

__device__ __forceinline__ float bf2f(unsigned short u){
    union { unsigned int ui; float f; } x; x.ui = ((unsigned int)u) << 16; return x.f;
}
// element load: f32 array or bf16 array, by flag
__device__ __forceinline__ float ldf(const void* p, size_t idx, bool f32){
    return f32 ? ((const float*)p)[idx] : bf2f(((const unsigned short*)p)[idx]);
}
// bf16 pattern of element (truncation for f32 — only used for the value GEMM inputs)
__device__ __forceinline__ unsigned short ldpat(const void* p, size_t idx, bool f32){
    return f32 ? (unsigned short)(((const unsigned int*)p)[idx] >> 16)
               : ((const unsigned short*)p)[idx];
}
// dist is uniform [0,1): as bf16 every u16 pattern < 0x3F80; as f32 low halves are ~uniform bits.
__device__ __forceinline__ bool sniff_f32(const void* dist){
    const unsigned int* d = (const unsigned int*)dist;
    unsigned int bad = 0;
    for (int k = (threadIdx.x & 63); k < 512; k += 64){
        unsigned int u = d[k];
        if ((u & 0xFFFFu) >= 0x3F80u || (u >> 16) >= 0x3F80u) bad = 1;
    }
    return __ballot(bad) != 0ull;
}
__device__ __forceinline__ int get_loc(const int* locp){
    int lr = locp[0];
    if (lr >= 0 && lr <= 100) return lr;
    float lf = __int_as_float(lr);
    if (lf >= 0.f && lf <= 100.f) return (int)(lf + 0.5f);
    return 64;
}
__device__ __forceinline__ float head_scale(const void* rr, int h, bool f32){
    float rf = ldf(rr, h, f32);
    float ts = tanf(0.78539816339744831f * (1.0f + sinf(rf)));
    if (!(ts > 0.f)) ts = (ts == 0.f) ? 1e-20f : 1e20f;  // 0 -> tiny; neg/NaN (pi/2 cross) -> huge
    if (ts > 1e20f) ts = 1e20f;
    return ts;
}

// ---------------------------------------------------------------------------
// K1: per row i of dist: Kval_i = rank-th smallest value (rank = floor(loc*(N-1)/100)+1),
// xmin_i = row min.  f32 path: value-bucket + exact rank among candidates.
// bf16 path: two-pass u16-pattern radix (nonneg: pattern order == value order).
// ---------------------------------------------------------------------------
__global__ __launch_bounds__(256) void k_rowstats(const void* __restrict__ dist,
                                                  const int* __restrict__ locp,
                                                  float* __restrict__ Kval,
                                                  float* __restrict__ xminp){
    __shared__ float rowf[NN];             // 16 KB (f32 path)
    __shared__ unsigned short rowh[NN];    // 8 KB (bf16 path)
    __shared__ unsigned int hist[256];
    __shared__ unsigned int minpat, selb, basec, cnt;
    __shared__ float cand[1024];
    const int i = blockIdx.x, t = threadIdx.x;
    const bool f32 = sniff_f32(dist);
    const int loc = get_loc(locp);
    const unsigned int rank = (unsigned int)(((long long)loc * (NN - 1)) / 100) + 1u; // in [1,NN]

    if (f32){
        const float4* rp = (const float4*)((const float*)dist + (size_t)i * NN);
        float4* rw = (float4*)rowf;
        for (int k = t; k < NN / 4; k += 256) rw[k] = rp[k];
        hist[t] = 0;
        if (t == 0){ minpat = 0xFFFFFFFFu; cnt = 0; selb = 255u; basec = 0u; }
        __syncthreads();
        unsigned int lmin = 0xFFFFFFFFu;
        for (int k = t; k < NN; k += 256){
            float x = rowf[k];
            int b = (int)(x * 256.0f); b = b < 0 ? 0 : (b > 255 ? 255 : b);
            atomicAdd(&hist[b], 1u);
            unsigned int p = __float_as_uint(x);      // nonneg: pattern order = value order
            lmin = p < lmin ? p : lmin;
        }
        atomicMin(&minpat, lmin);
        __syncthreads();
        if (t == 0){
            unsigned int c = 0;
            for (int b = 0; b < 256; b++){
                unsigned int c2 = c + hist[b];
                if (c2 >= rank){ selb = (unsigned int)b; basec = c; break; }
                c = c2;
            }
        }
        __syncthreads();
        const unsigned int sb = selb;
        for (int k = t; k < NN; k += 256){
            float x = rowf[k];
            int b = (int)(x * 256.0f); b = b < 0 ? 0 : (b > 255 ? 255 : b);
            if ((unsigned int)b == sb){
                unsigned int idx = atomicAdd(&cnt, 1u);
                if (idx < 1024u) cand[idx] = x;
            }
        }
        __syncthreads();
        const unsigned int n = cnt > 1024u ? 1024u : cnt;
        const unsigned int need = rank - basec;       // 1-based rank within bucket
        if (t == 0 && (n == 0 || need > n)) Kval[i] = ((float)selb + 1.0f) / 256.0f; // safety
        for (unsigned int c0 = t; c0 < n; c0 += 256){
            float x = cand[c0];
            unsigned int lt = 0, le = 0;
            for (unsigned int k2 = 0; k2 < n; k2++){
                float y = cand[k2];
                lt += (y < x); le += (y <= x);
            }
            if (lt < need && need <= le) Kval[i] = x;
        }
        if (t == 0) xminp[i] = __uint_as_float(minpat);
    } else {
        const unsigned int* rp = (const unsigned int*)((const unsigned short*)dist + (size_t)i * NN);
        unsigned int* rw = (unsigned int*)rowh;
        for (int k = t; k < NN / 2; k += 256) rw[k] = rp[k];
        hist[t] = 0;
        if (t == 0){ minpat = 0xFFFFFFFFu; selb = 0u; basec = 0u; }
        __syncthreads();
        unsigned int lmin = 0xFFFFu;
        for (int k = t; k < NN; k += 256){
            unsigned int p = rowh[k];
            atomicAdd(&hist[p >> 8], 1u);
            lmin = p < lmin ? p : lmin;
        }
        atomicMin(&minpat, lmin);
        __syncthreads();
        if (t == 0){
            unsigned int c = 0;
            for (int b = 0; b < 256; b++){
                unsigned int c2 = c + hist[b];
                if (c2 >= rank){ selb = (unsigned int)b; basec = c; break; }
                c = c2;
            }
        }
        __syncthreads();
        const unsigned int hi = selb, base = basec;
        hist[t] = 0;
        __syncthreads();
        for (int k = t; k < NN; k += 256){
            unsigned int p = rowh[k];
            if ((p >> 8) == hi) atomicAdd(&hist[p & 0xFFu], 1u);
        }
        __syncthreads();
        if (t == 0){
            unsigned int c = base;
            unsigned int kp = (hi << 8) | 0xFFu;
            for (int b = 0; b < 256; b++){
                c += hist[b];
                if (c >= rank){ kp = (hi << 8) | (unsigned int)b; break; }
            }
            Kval[i]  = bf2f((unsigned short)kp);
            xminp[i] = bf2f((unsigned short)minpat);
        }
    }
}

// ---------------------------------------------------------------------------
// K2 (path A): val[h][j][b*V+d] = sum_c in[b][j][c] * wgt[h][c][d], f32 out.
// grid (NN/16, NH), block 256. insh [c][r], r = jl*4+b, stride 65.
// ---------------------------------------------------------------------------
__global__ __launch_bounds__(256) void k_value(const void* __restrict__ in,
                                               const void* __restrict__ wgt,
                                               const void* __restrict__ dist,
                                               float* __restrict__ val){
    __shared__ float insh[NC * 65];   // 33.3 KB
    __shared__ float wsh[NC * NV];    // 8 KB
    const bool f32 = sniff_f32(dist);
    const int j0 = blockIdx.x * 16;
    const int h  = blockIdx.y;
    const int t  = threadIdx.x;

    for (int k = t; k < NC * NV; k += 256) wsh[k] = ldf(wgt, (size_t)h * NC * NV + k, f32);

#pragma unroll
    for (int k = 0; k < 32; k++){
        int idx = k * 256 + t;            // 8192 = 64 rows x 128 c
        int p = idx >> 7, c = idx & 127;
        int b = p >> 4, jl = p & 15;
        float x = ldf(in, ((size_t)b * NN + j0 + jl) * NC + c, f32);
        insh[c * 65 + jl * 4 + b] = x;
    }
    __syncthreads();

    const int r = t & 63, dq = t >> 6;
    const int jl = r >> 2, b = r & 3;
    float acc0 = 0.f, acc1 = 0.f, acc2 = 0.f, acc3 = 0.f;
#pragma unroll 8
    for (int c = 0; c < NC; c++){
        float x = insh[c * 65 + r];
        float4 w4 = *(const float4*)&wsh[c * NV + dq * 4];
        acc0 = fmaf(x, w4.x, acc0);
        acc1 = fmaf(x, w4.y, acc1);
        acc2 = fmaf(x, w4.z, acc2);
        acc3 = fmaf(x, w4.w, acc3);
    }
    float4* op = (float4*)&val[(((size_t)h * NN + j0 + jl) * NB + b) * NV + dq * 4];
    *op = make_float4(acc0, acc1, acc2, acc3);
}

// ---------------------------------------------------------------------------
// K3 (path A): per (64-i-tile, head): loop 64-j tiles:
//   w(i,j) = (x <= Kval_i) ? exp(ts*(xmin_i - x)) : 0  (wsh [j][i], stride 68)
//   acc[i][bd] += w * v[j][bd]; S_i += w.  Epilogue: gelu(acc/S), dual-dtype out.
// ---------------------------------------------------------------------------
__global__ __launch_bounds__(256) void k_att(const void* __restrict__ dist,
                                             const void* __restrict__ rr,
                                             const float* __restrict__ val,
                                             const float* __restrict__ Kvalp,
                                             const float* __restrict__ xminp,
                                             void* __restrict__ out){
    __shared__ float vsh[64 * BD];      // [jl][bd]
    __shared__ float wsh[64 * 68];      // [jl][il]
    __shared__ float kv[64], xm[64], ssh[64];

    const bool f32 = sniff_f32(dist);
    const int i0 = blockIdx.x * 64;
    const int h  = blockIdx.y;
    const int t  = threadIdx.x;
    const int tx = t & 15, ty = t >> 4;
    const float ts = head_scale(rr, h, f32);

    if (t < 64){ kv[t] = Kvalp[i0 + t]; xm[t] = xminp[i0 + t]; }

    float acc[4][4];
#pragma unroll
    for (int q = 0; q < 4; q++)
#pragma unroll
        for (int p = 0; p < 4; p++) acc[q][p] = 0.f;
    float s_priv = 0.f;

    const int jj = t & 63, a = t >> 6;

    for (int jt = 0; jt < NN / 64; jt++){
        const int j0 = jt * 64;
        __syncthreads();

#pragma unroll
        for (int k = 0; k < 4; k++){
            int idx = k * 256 + t;
            int jl = idx >> 4, f4 = idx & 15;
            ((float4*)vsh)[jl * 16 + f4] = ((const float4*)val)[((size_t)h * NN + j0 + jl) * 16 + f4];
        }
#pragma unroll
        for (int m = 0; m < 4; m++){
            float wq[4];
#pragma unroll
            for (int q = 0; q < 4; q++){
                int il = 16 * a + 4 * m + q;
                float x = ldf(dist, (size_t)(i0 + il) * NN + j0 + jj, f32);
                wq[q] = (x <= kv[il]) ? __expf(ts * (xm[il] - x)) : 0.f;
            }
            *(float4*)&wsh[jj * 68 + 16 * a + 4 * m] = make_float4(wq[0], wq[1], wq[2], wq[3]);
        }
        __syncthreads();

#pragma unroll 4
        for (int j = 0; j < 64; j++){
            float4 vv = *(const float4*)&vsh[j * BD + 4 * tx];
            float4 ww = *(const float4*)&wsh[j * 68 + 4 * ty];
            acc[0][0] = fmaf(ww.x, vv.x, acc[0][0]);
            acc[0][1] = fmaf(ww.x, vv.y, acc[0][1]);
            acc[0][2] = fmaf(ww.x, vv.z, acc[0][2]);
            acc[0][3] = fmaf(ww.x, vv.w, acc[0][3]);
            acc[1][0] = fmaf(ww.y, vv.x, acc[1][0]);
            acc[1][1] = fmaf(ww.y, vv.y, acc[1][1]);
            acc[1][2] = fmaf(ww.y, vv.z, acc[1][2]);
            acc[1][3] = fmaf(ww.y, vv.w, acc[1][3]);
            acc[2][0] = fmaf(ww.z, vv.x, acc[2][0]);
            acc[2][1] = fmaf(ww.z, vv.y, acc[2][1]);
            acc[2][2] = fmaf(ww.z, vv.z, acc[2][2]);
            acc[2][3] = fmaf(ww.z, vv.w, acc[2][3]);
            acc[3][0] = fmaf(ww.w, vv.x, acc[3][0]);
            acc[3][1] = fmaf(ww.w, vv.y, acc[3][1]);
            acc[3][2] = fmaf(ww.w, vv.z, acc[3][2]);
            acc[3][3] = fmaf(ww.w, vv.w, acc[3][3]);
        }
        if (t < 64){
            float s = 0.f;
#pragma unroll 8
            for (int j = 0; j < 64; j++) s += wsh[j * 68 + t];
            s_priv += s;
        }
    }

    __syncthreads();
    if (t < 64) ssh[t] = s_priv;
    __syncthreads();

#pragma unroll
    for (int q = 0; q < 4; q++){
        const int i = 4 * ty + q;
        const float inv_s = 1.0f / fmaxf(ssh[i], 1e-30f);
        const size_t gi = (size_t)(i0 + i);
        const int b = tx >> 2, dq = (tx & 3) * 4;
        float g[4];
#pragma unroll
        for (int p = 0; p < 4; p++){
            float c = acc[q][p] * inv_s;
            float gg = 0.5f * c * (1.0f + erff(c * 0.70710678118654752f));
            g[p] = isfinite(gg) ? gg : 0.f;
        }
        const size_t off = ((size_t)b * NN + gi) * (NH * NV) + h * NV + dq;
        if (f32){
            *(float4*)&((float*)out)[off] = make_float4(g[0], g[1], g[2], g[3]);
        } else {
            unsigned short o[4];
#pragma unroll
            for (int p = 0; p < 4; p++){
                __hip_bfloat16 hb = __float2bfloat16(g[p]);
                o[p] = __builtin_bit_cast(unsigned short, hb);
            }
            *(ushort4*)&((unsigned short*)out)[off] = make_ushort4(o[0], o[1], o[2], o[3]);
        }
    }
}

// ---------------------------------------------------------------------------
// Path B: fused k_att with in-block value recomputation (needs only 32 KB ws).
// Per (64-i-tile, head): per j-tile: stage inputs (bf16 patterns) + W, compute
// vtile = in x W, then same att accumulation as path A.
// ---------------------------------------------------------------------------
__global__ __launch_bounds__(256) void k_att_nv(const void* __restrict__ dist,
                                                const void* __restrict__ rr,
                                                const void* __restrict__ in,
                                                const void* __restrict__ wgt,
                                                const float* __restrict__ Kvalp,
                                                const float* __restrict__ xminp,
                                                void* __restrict__ out){
    __shared__ unsigned short in_sh[256 * 130];  // 66.6 KB [jb][c], jb = jl*4+b
    __shared__ float Wf[NC * NV];                // 8 KB [c][v]
    __shared__ float vsh[64 * 68];               // 17.4 KB [jl][bd]
    __shared__ float wsh[64 * 68];               // 17.4 KB [jl][il]
    __shared__ float kv[64], xm[64], ssh[64];

    const bool f32 = sniff_f32(dist);
    const int i0 = blockIdx.x * 64;
    const int h  = blockIdx.y;
    const int t  = threadIdx.x;
    const int tx = t & 15, ty = t >> 4;
    const float ts = head_scale(rr, h, f32);

    if (t < 64){ kv[t] = Kvalp[i0 + t]; xm[t] = xminp[i0 + t]; }
    for (int k = t; k < NC * NV; k += 256) Wf[k] = ldf(wgt, (size_t)h * NC * NV + k, f32);

    float acc[4][4];
#pragma unroll
    for (int q = 0; q < 4; q++)
#pragma unroll
        for (int p = 0; p < 4; p++) acc[q][p] = 0.f;
    float s_priv = 0.f;

    const int jj = t & 63, a = t >> 6;
    const int vj = t >> 2, vb = t & 3;          // value-phase: thread -> (j, b)

    for (int jt = 0; jt < NN / 64; jt++){
        const int j0 = jt * 64;
        __syncthreads();   // prev iter fully consumed (vsh/wsh/in_sh)

        // stage input tile as bf16 patterns: rows p=(jl*4+b) x 128 c
        for (int k = 0; k < 128; k++){
            int idx = k * 256 + t;               // 32768 = 256 rows x 128 c
            int p = idx >> 7, c = idx & 127;
            int jl = p >> 2, b = p & 3;
            in_sh[p * 130 + c] = ldpat(in, ((size_t)b * NN + j0 + jl) * NC + c, f32);
        }
        // stage w tile (full-precision dist)
#pragma unroll
        for (int m = 0; m < 4; m++){
            float wq[4];
#pragma unroll
            for (int q = 0; q < 4; q++){
                int il = 16 * a + 4 * m + q;
                float x = ldf(dist, (size_t)(i0 + il) * NN + j0 + jj, f32);
                wq[q] = (x <= kv[il]) ? __expf(ts * (xm[il] - x)) : 0.f;
            }
            *(float4*)&wsh[jj * 68 + 16 * a + 4 * m] = make_float4(wq[0], wq[1], wq[2], wq[3]);
        }
        __syncthreads();

        // value phase: thread (vj, vb) computes vtile[vj][vb*16 + 0..15]
        {
            float a16[16];
#pragma unroll
            for (int v = 0; v < 16; v++) a16[v] = 0.f;
            const unsigned short* ip = &in_sh[t * 130];   // row jb = vj*4+vb = t
#pragma unroll 2
            for (int c = 0; c < NC; c++){
                float x = bf2f(ip[c]);
                const float* wr = &Wf[c * NV];
#pragma unroll
                for (int v = 0; v < 16; v++) a16[v] = fmaf(x, wr[v], a16[v]);
            }
            float* vp = &vsh[vj * 68 + vb * 16];
#pragma unroll
            for (int v4 = 0; v4 < 4; v4++)
                *(float4*)&vp[4 * v4] = make_float4(a16[4*v4], a16[4*v4+1], a16[4*v4+2], a16[4*v4+3]);
        }
        __syncthreads();

        // att accumulation
#pragma unroll 4
        for (int j = 0; j < 64; j++){
            float4 vv = *(const float4*)&vsh[j * 68 + 4 * tx];
            float4 ww = *(const float4*)&wsh[j * 68 + 4 * ty];
            acc[0][0] = fmaf(ww.x, vv.x, acc[0][0]);
            acc[0][1] = fmaf(ww.x, vv.y, acc[0][1]);
            acc[0][2] = fmaf(ww.x, vv.z, acc[0][2]);
            acc[0][3] = fmaf(ww.x, vv.w, acc[0][3]);
            acc[1][0] = fmaf(ww.y, vv.x, acc[1][0]);
            acc[1][1] = fmaf(ww.y, vv.y, acc[1][1]);
            acc[1][2] = fmaf(ww.y, vv.z, acc[1][2]);
            acc[1][3] = fmaf(ww.y, vv.w, acc[1][3]);
            acc[2][0] = fmaf(ww.z, vv.x, acc[2][0]);
            acc[2][1] = fmaf(ww.z, vv.y, acc[2][1]);
            acc[2][2] = fmaf(ww.z, vv.z, acc[2][2]);
            acc[2][3] = fmaf(ww.z, vv.w, acc[2][3]);
            acc[3][0] = fmaf(ww.w, vv.x, acc[3][0]);
            acc[3][1] = fmaf(ww.w, vv.y, acc[3][1]);
            acc[3][2] = fmaf(ww.w, vv.z, acc[3][2]);
            acc[3][3] = fmaf(ww.w, vv.w, acc[3][3]);
        }
        if (t < 64){
            float s = 0.f;
#pragma unroll 8
            for (int j = 0; j < 64; j++) s += wsh[j * 68 + t];
            s_priv += s;
        }
    }

    __syncthreads();
    if (t < 64) ssh[t] = s_priv;
    __syncthreads();

#pragma unroll
    for (int q = 0; q < 4; q++){
        const int i = 4 * ty + q;
        const float inv_s = 1.0f / fmaxf(ssh[i], 1e-30f);
        const size_t gi = (size_t)(i0 + i);
        const int b = tx >> 2, dq = (tx & 3) * 4;
        float g[4];
#pragma unroll
        for (int p = 0; p < 4; p++){
            float c = acc[q][p] * inv_s;
            float gg = 0.5f * c * (1.0f + erff(c * 0.70710678118654752f));
            g[p] = isfinite(gg) ? gg : 0.f;
        }
        const size_t off = ((size_t)b * NN + gi) * (NH * NV) + h * NV + dq;
        if (f32){
            *(float4*)&((float*)out)[off] = make_float4(g[0], g[1], g[2], g[3]);
        } else {
            unsigned short o[4];
#pragma unroll
            for (int p = 0; p < 4; p++){
                __hip_bfloat16 hb = __float2bfloat16(g[p]);
                o[p] = __builtin_bit_cast(unsigned short, hb);
            }
            *(ushort4*)&((unsigned short*)out)[off] = make_ushort4(o[0], o[1], o[2], o[3]);
        }
    }
}

// ---------------------------------------------------------------------------
extern "C" void kernel_launch(void* const* d_in, const int* in_sizes, int n_in,
                              void* d_out, int out_size, void* d_ws, size_t ws_size,
                              hipStream_t stream) {
    const void* in   = d_in[0];            // (B,N,C)
    const void* dist = d_in[1];            // (N,N)
    const void* r    = d_in[2];            // (H,1,1)
    const void* wgt  = d_in[3];            // (H,C,V)
    const int*  loc  = (const int*)d_in[4];

    float* Kval = (float*)d_ws;
    float* xmin = Kval + NN;
    const size_t stats_bytes = 2 * (size_t)NN * sizeof(float);          // 32 KB
    float* val = (float*)((char*)d_ws + stats_bytes);
    const size_t need_full = stats_bytes + (size_t)NH * NN * BD * sizeof(float); // +8 MB

    k_rowstats<<<NN, 256, 0, stream>>>(dist, loc, Kval, xmin);
    if (ws_size >= need_full){
        k_value<<<dim3(NN / 16, NH), 256, 0, stream>>>(in, wgt, dist, val);
        k_att<<<dim3(NN / 64, NH), 256, 0, stream>>>(dist, r, val, Kval, xmin, d_out);
    } else {
        k_att_nv<<<dim3(NN / 64, NH), 256, 0, stream>>>(dist, r, in, wgt, Kval, xmin, d_out);
    }
}

// Round 6
// 285.404 us; speedup vs baseline: 2.4643x; 2.4643x over previous
//
#include <hip/hip_runtime.h>
#include <hip/hip_bf16.h>
#include <math.h>

#define NN 4096
#define NC 128
#define NH 8
#define NV 16
#define NB 4
#define BD 64   // NB*NV

typedef _Float16 half8 __attribute__((ext_vector_type(8)));
typedef float floatx4 __attribute__((ext_vector_type(4)));

__device__ __forceinline__ int get_loc(const int* locp){
    int lr = locp[0];
    return (lr >= 0 && lr <= 100) ? lr : 64;
}
__device__ __forceinline__ float head_scale(const float* rr, int h){
    float ts = tanf(0.78539816339744831f * (1.0f + sinf(rr[h])));
    if (!(ts > 0.f)) ts = (ts == 0.f) ? 1e-20f : 1e20f;
    if (ts > 1e20f) ts = 1e20f;
    return ts;
}

// ---------------------------------------------------------------------------
// K1: per row i of dist (f32, in [0,1)): Kval_i = rank-th smallest value
// (rank = floor(loc*(N-1)/100)+1), xmin_i = row min.  Value-bucket select.
// (Unchanged from R5's passing f32 path.)
// ---------------------------------------------------------------------------
__global__ __launch_bounds__(256) void k_rowstats(const float* __restrict__ dist,
                                                  const int* __restrict__ locp,
                                                  float* __restrict__ Kval,
                                                  float* __restrict__ xminp){
    __shared__ float rowf[NN];
    __shared__ unsigned int hist[256];
    __shared__ unsigned int minpat, selb, basec, cnt;
    __shared__ float cand[1024];
    const int i = blockIdx.x, t = threadIdx.x;
    const int loc = get_loc(locp);
    const unsigned int rank = (unsigned int)(((long long)loc * (NN - 1)) / 100) + 1u;

    const float4* rp = (const float4*)(dist + (size_t)i * NN);
    float4* rw = (float4*)rowf;
    for (int k = t; k < NN / 4; k += 256) rw[k] = rp[k];
    hist[t] = 0;
    if (t == 0){ minpat = 0xFFFFFFFFu; cnt = 0; selb = 255u; basec = 0u; }
    __syncthreads();
    unsigned int lmin = 0xFFFFFFFFu;
    for (int k = t; k < NN; k += 256){
        float x = rowf[k];
        int b = (int)(x * 256.0f); b = b < 0 ? 0 : (b > 255 ? 255 : b);
        atomicAdd(&hist[b], 1u);
        unsigned int p = __float_as_uint(x);
        lmin = p < lmin ? p : lmin;
    }
    atomicMin(&minpat, lmin);
    __syncthreads();
    if (t == 0){
        unsigned int c = 0;
        for (int b = 0; b < 256; b++){
            unsigned int c2 = c + hist[b];
            if (c2 >= rank){ selb = (unsigned int)b; basec = c; break; }
            c = c2;
        }
    }
    __syncthreads();
    const unsigned int sb = selb;
    for (int k = t; k < NN; k += 256){
        float x = rowf[k];
        int b = (int)(x * 256.0f); b = b < 0 ? 0 : (b > 255 ? 255 : b);
        if ((unsigned int)b == sb){
            unsigned int idx = atomicAdd(&cnt, 1u);
            if (idx < 1024u) cand[idx] = x;
        }
    }
    __syncthreads();
    const unsigned int n = cnt > 1024u ? 1024u : cnt;
    const unsigned int need = rank - basec;
    if (t == 0 && (n == 0 || need > n)) Kval[i] = ((float)selb + 1.0f) / 256.0f;
    for (unsigned int c0 = t; c0 < n; c0 += 256){
        float x = cand[c0];
        unsigned int lt = 0, le = 0;
        for (unsigned int k2 = 0; k2 < n; k2++){
            float y = cand[k2];
            lt += (y < x); le += (y <= x);
        }
        if (lt < need && need <= le) Kval[i] = x;
    }
    if (t == 0) xminp[i] = __uint_as_float(minpat);
}

// ---------------------------------------------------------------------------
// K2: val_t[h][bd][j] = sum_c in[b][j][c] * wgt[h][c][d], bd = b*16+d, f16 out.
// grid (NN/16, NH), block 256. insh [c][r], r = jl*4+b, stride 65.
// ---------------------------------------------------------------------------
__global__ __launch_bounds__(256) void k_value(const float* __restrict__ in,
                                               const float* __restrict__ wgt,
                                               _Float16* __restrict__ val_t){
    __shared__ float insh[NC * 65];
    __shared__ float wsh[NC * NV];
    const int j0 = blockIdx.x * 16;
    const int h  = blockIdx.y;
    const int t  = threadIdx.x;

    for (int k = t; k < NC * NV; k += 256) wsh[k] = wgt[h * NC * NV + k];
#pragma unroll
    for (int k = 0; k < 32; k++){
        int idx = k * 256 + t;            // 8192 = 64 rows x 128 c
        int p = idx >> 7, c = idx & 127;
        int b = p >> 4, jl = p & 15;
        insh[c * 65 + jl * 4 + b] = in[((size_t)b * NN + j0 + jl) * NC + c];
    }
    __syncthreads();

    const int r = t & 63, dq = t >> 6;
    const int jl = r >> 2, b = r & 3;
    float a0 = 0.f, a1 = 0.f, a2 = 0.f, a3 = 0.f;
#pragma unroll 8
    for (int c = 0; c < NC; c++){
        float x = insh[c * 65 + r];
        float4 w4 = *(const float4*)&wsh[c * NV + dq * 4];
        a0 = fmaf(x, w4.x, a0);
        a1 = fmaf(x, w4.y, a1);
        a2 = fmaf(x, w4.z, a2);
        a3 = fmaf(x, w4.w, a3);
    }
    const size_t base = ((size_t)(h * BD + b * NV + dq * 4)) * NN + j0 + jl;
    val_t[base         ] = (_Float16)a0;
    val_t[base + NN    ] = (_Float16)a1;
    val_t[base + 2 * NN] = (_Float16)a2;
    val_t[base + 3 * NN] = (_Float16)a3;
}

// ---------------------------------------------------------------------------
// K3 (MFMA): per (64-i tile, head): K-loop over 64-j tiles.
//   wtile[i][j] (f16, stride 72) = masked exp; vtile[bd][j] (f16, stride 72).
//   Wave w computes i-strip [16w,16w+16) x all 64 bd via 16x16x32 f16 MFMA.
//   Denominator: quad shuffles during w-staging. Epilogue: gelu(acc/S) f32 out.
// ---------------------------------------------------------------------------
__global__ __launch_bounds__(256) void k_att(const float* __restrict__ dist,
                                             const float* __restrict__ rr,
                                             const _Float16* __restrict__ val_t,
                                             const float* __restrict__ Kvalp,
                                             const float* __restrict__ xminp,
                                             float* __restrict__ out){
    __shared__ alignas(16) _Float16 wtile[64 * 72];   // [i][j]  9216 B
    __shared__ alignas(16) _Float16 vtile[64 * 72];   // [bd][j] 9216 B
    __shared__ float kv[64], xm[64], ssh[64];

    const int i0 = blockIdx.x * 64;
    const int h  = blockIdx.y;
    const int t  = threadIdx.x;
    const int lane = t & 63, wv = t >> 6;
    const float ts = head_scale(rr, h);

    if (t < 64){ kv[t] = Kvalp[i0 + t]; xm[t] = xminp[i0 + t]; }

    floatx4 acc[4];
#pragma unroll
    for (int nt = 0; nt < 4; nt++) acc[nt] = (floatx4){0.f, 0.f, 0.f, 0.f};
    float s_priv = 0.f;

    const int il = t >> 2, jq = t & 3;           // w-staging: 16 j's per thread
    const int vbd = t >> 3, vpart = t & 7;       // v-staging: 8 f16 per thread

    for (int jt = 0; jt < NN / 64; jt++){
        const int j0 = jt * 64;
        __syncthreads();   // prev tile consumed (also publishes kv/xm on iter 0)

        // stage v: val_t rows are f16-contiguous in j -> uint4 = 8 f16
#pragma unroll
        for (int k2 = 0; k2 < 2; k2++){
            int bd = vbd + 32 * k2;
            *(uint4*)&vtile[bd * 72 + vpart * 8] =
                *(const uint4*)&val_t[((size_t)(h * BD + bd)) * NN + j0 + vpart * 8];
        }
        // stage w: 16 dist values, mask+exp, f16 pack, quad-reduce denominator
        {
            const float kvi = kv[il], xmi = xm[il];
            float wf[16];
#pragma unroll
            for (int u = 0; u < 4; u++){
                float4 d4 = *(const float4*)&dist[(size_t)(i0 + il) * NN + j0 + jq * 16 + 4 * u];
                wf[4*u+0] = (d4.x <= kvi) ? __expf(ts * (xmi - d4.x)) : 0.f;
                wf[4*u+1] = (d4.y <= kvi) ? __expf(ts * (xmi - d4.y)) : 0.f;
                wf[4*u+2] = (d4.z <= kvi) ? __expf(ts * (xmi - d4.z)) : 0.f;
                wf[4*u+3] = (d4.w <= kvi) ? __expf(ts * (xmi - d4.w)) : 0.f;
            }
            float s16 = 0.f;
#pragma unroll
            for (int u = 0; u < 16; u++) s16 += wf[u];
            s16 += __shfl_xor(s16, 1);
            s16 += __shfl_xor(s16, 2);
            if (jq == 0) s_priv += s16;
            half8 h0, h1;
#pragma unroll
            for (int u = 0; u < 8; u++){ h0[u] = (_Float16)wf[u]; h1[u] = (_Float16)wf[u + 8]; }
            *(half8*)&wtile[il * 72 + jq * 16    ] = h0;
            *(half8*)&wtile[il * 72 + jq * 16 + 8] = h1;
        }
        __syncthreads();

        // MFMA: wave wv does i-strip 16*wv..+16, all 64 bd, K=64 in 2 chunks
#pragma unroll
        for (int kc = 0; kc < 2; kc++){
            half8 af = *(half8*)&wtile[(16 * wv + (lane & 15)) * 72 + kc * 32 + (lane >> 4) * 8];
#pragma unroll
            for (int nt = 0; nt < 4; nt++){
                half8 bf = *(half8*)&vtile[(nt * 16 + (lane & 15)) * 72 + kc * 32 + (lane >> 4) * 8];
                acc[nt] = __builtin_amdgcn_mfma_f32_16x16x32_f16(af, bf, acc[nt], 0, 0, 0);
            }
        }
    }

    if (jq == 0) ssh[il] = s_priv;
    __syncthreads();

    // epilogue: D[m][n]: m = (lane>>4)*4 + reg (i-local in strip), n = lane&15
    const int m0 = 16 * wv + (lane >> 4) * 4;
    const int d  = lane & 15;
#pragma unroll
    for (int r4 = 0; r4 < 4; r4++){
        const int iloc = m0 + r4;
        const float inv_s = 1.0f / fmaxf(ssh[iloc], 1e-30f);
#pragma unroll
        for (int nt = 0; nt < 4; nt++){   // nt == batch b (bd = nt*16 + d)
            float c = acc[nt][r4] * inv_s;
            float g = 0.5f * c * (1.0f + erff(c * 0.70710678118654752f));
            out[((size_t)nt * NN + i0 + iloc) * (NH * NV) + h * NV + d] = g;
        }
    }
}

// ---------------------------------------------------------------------------
extern "C" void kernel_launch(void* const* d_in, const int* in_sizes, int n_in,
                              void* d_out, int out_size, void* d_ws, size_t ws_size,
                              hipStream_t stream) {
    const float* in   = (const float*)d_in[0]; // (B,N,C) f32
    const float* dist = (const float*)d_in[1]; // (N,N) f32
    const float* r    = (const float*)d_in[2]; // (H,1,1) f32
    const float* wgt  = (const float*)d_in[3]; // (H,C,V) f32
    const int*   loc  = (const int*)d_in[4];   // scalar int
    float* out = (float*)d_out;                // (B,N,H*V) f32

    float* Kval = (float*)d_ws;
    float* xmin = Kval + NN;
    _Float16* val_t = (_Float16*)((char*)d_ws + 2 * (size_t)NN * sizeof(float)); // 4 MB

    k_rowstats<<<NN, 256, 0, stream>>>(dist, loc, Kval, xmin);
    k_value<<<dim3(NN / 16, NH), 256, 0, stream>>>(in, wgt, val_t);
    k_att<<<dim3(NN / 64, NH), 256, 0, stream>>>(dist, r, val_t, Kval, xmin, out);
}

// Round 7
// 207.246 us; speedup vs baseline: 3.3936x; 1.3771x over previous
//
#include <hip/hip_runtime.h>
#include <hip/hip_bf16.h>
#include <math.h>

#define NN 4096
#define NC 128
#define NH 8
#define NV 16
#define NB 4
#define BD 64   // NB*NV

typedef _Float16 half8 __attribute__((ext_vector_type(8)));
typedef float floatx4 __attribute__((ext_vector_type(4)));

__device__ __forceinline__ int get_loc(const int* locp){
    int lr = locp[0];
    return (lr >= 0 && lr <= 100) ? lr : 64;
}
__device__ __forceinline__ float head_scale(const float* rr, int h){
    float ts = tanf(0.78539816339744831f * (1.0f + sinf(rr[h])));
    if (!(ts > 0.f)) ts = (ts == 0.f) ? 1e-20f : 1e20f;
    if (ts > 1e20f) ts = 1e20f;
    return ts;
}

// ---------------------------------------------------------------------------
// K1: per row i of dist (f32 in [0,1)): Kval_i = rank-th smallest
// (rank = floor(loc*(N-1)/100)+1), xmin_i = row min.
// Register-resident values; wave-private 256-bin hist; shfl-scan selection.
// ---------------------------------------------------------------------------
__global__ __launch_bounds__(256) void k_rowstats(const float* __restrict__ dist,
                                                  const int* __restrict__ locp,
                                                  float* __restrict__ Kval,
                                                  float* __restrict__ xminp){
    __shared__ unsigned int hist[4][256];   // per-wave private
    __shared__ float cand[1024];
    __shared__ unsigned int cnt, selb_s, basec_s, xminu;
    const int i = blockIdx.x, t = threadIdx.x;
    const int wv = t >> 6, lane = t & 63;
    const int loc = get_loc(locp);
    const unsigned int rank = (unsigned int)(((long long)loc * (NN - 1)) / 100) + 1u;

    // load 16 values, coalesced float4
    float v[16];
    const float4* rp = (const float4*)(dist + (size_t)i * NN);
#pragma unroll
    for (int k = 0; k < 4; k++){
        float4 x4 = rp[k * 256 + t];
        v[4*k+0] = x4.x; v[4*k+1] = x4.y; v[4*k+2] = x4.z; v[4*k+3] = x4.w;
    }
    for (int k = t; k < 1024; k += 256) ((unsigned int*)hist)[k] = 0;
    if (t == 0){ cnt = 0; selb_s = 255u; basec_s = 0u; xminu = 0xFFFFFFFFu; }
    __syncthreads();

    float lmin = 1e30f;
#pragma unroll
    for (int u = 0; u < 16; u++){
        float x = v[u];
        lmin = fminf(lmin, x);
        int b = (int)(x * 256.0f); b = b < 0 ? 0 : (b > 255 ? 255 : b);
        atomicAdd(&hist[wv][b], 1u);
    }
#pragma unroll
    for (int off = 1; off < 64; off <<= 1) lmin = fminf(lmin, __shfl_xor(lmin, off));
    if (lane == 0) atomicMin(&xminu, __float_as_uint(lmin));   // nonneg: pattern order
    __syncthreads();

    // wave0: lane l owns bins 4l..4l+3; shfl inclusive scan over lane sums
    if (t < 64){
        unsigned int lp[4];
        unsigned int run = 0;
#pragma unroll
        for (int q = 0; q < 4; q++){
            int b = 4 * t + q;
            run += hist[0][b] + hist[1][b] + hist[2][b] + hist[3][b];
            lp[q] = run;
        }
        unsigned int incl = run;
#pragma unroll
        for (int d = 1; d < 64; d <<= 1){
            unsigned int y = __shfl_up(incl, d);
            if (t >= d) incl += y;
        }
        unsigned int excl = incl - run;
        if (excl < rank && rank <= incl){
#pragma unroll
            for (int q = 0; q < 4; q++){
                if (excl + lp[q] >= rank){
                    selb_s  = (unsigned int)(4 * t + q);
                    basec_s = excl + (q ? lp[q-1] : 0u);
                    break;
                }
            }
        }
    }
    __syncthreads();
    const unsigned int sb = selb_s;
    if (t == 0) Kval[i] = ((float)sb + 1.0f) * 0.00390625f;   // fallback (overwritten below)
#pragma unroll
    for (int u = 0; u < 16; u++){
        float x = v[u];
        int b = (int)(x * 256.0f); b = b < 0 ? 0 : (b > 255 ? 255 : b);
        if ((unsigned int)b == (int)sb){
            unsigned int idx = atomicAdd(&cnt, 1u);
            if (idx < 1024u) cand[idx] = x;
        }
    }
    __syncthreads();
    const unsigned int n = cnt > 1024u ? 1024u : cnt;
    const unsigned int need = rank - basec_s;
    for (unsigned int c0 = t; c0 < n; c0 += 256){
        float x = cand[c0];
        unsigned int lt = 0, le = 0;
        for (unsigned int k2 = 0; k2 < n; k2++){
            float y = cand[k2];
            lt += (y < x); le += (y <= x);
        }
        if (lt < need && need <= le) Kval[i] = x;
    }
    if (t == 0) xminp[i] = __uint_as_float(xminu);
}

// ---------------------------------------------------------------------------
// K2: val_t[h][bd][j] = sum_c in[b][j][c] * wgt[h][c][d], bd = b*16+d, f16.
// (unchanged from R6 — passed)
// ---------------------------------------------------------------------------
__global__ __launch_bounds__(256) void k_value(const float* __restrict__ in,
                                               const float* __restrict__ wgt,
                                               _Float16* __restrict__ val_t){
    __shared__ float insh[NC * 65];
    __shared__ float wsh[NC * NV];
    const int j0 = blockIdx.x * 16;
    const int h  = blockIdx.y;
    const int t  = threadIdx.x;

    for (int k = t; k < NC * NV; k += 256) wsh[k] = wgt[h * NC * NV + k];
#pragma unroll
    for (int k = 0; k < 32; k++){
        int idx = k * 256 + t;
        int p = idx >> 7, c = idx & 127;
        int b = p >> 4, jl = p & 15;
        insh[c * 65 + jl * 4 + b] = in[((size_t)b * NN + j0 + jl) * NC + c];
    }
    __syncthreads();

    const int r = t & 63, dq = t >> 6;
    const int jl = r >> 2, b = r & 3;
    float a0 = 0.f, a1 = 0.f, a2 = 0.f, a3 = 0.f;
#pragma unroll 8
    for (int c = 0; c < NC; c++){
        float x = insh[c * 65 + r];
        float4 w4 = *(const float4*)&wsh[c * NV + dq * 4];
        a0 = fmaf(x, w4.x, a0);
        a1 = fmaf(x, w4.y, a1);
        a2 = fmaf(x, w4.z, a2);
        a3 = fmaf(x, w4.w, a3);
    }
    const size_t base = ((size_t)(h * BD + b * NV + dq * 4)) * NN + j0 + jl;
    val_t[base         ] = (_Float16)a0;
    val_t[base + NN    ] = (_Float16)a1;
    val_t[base + 2 * NN] = (_Float16)a2;
    val_t[base + 3 * NN] = (_Float16)a3;
}

// ---------------------------------------------------------------------------
// K3 (MFMA): 32-i tiles, grid (NN/32, NH) = 1024 blocks (4/CU).
// Wave wv: i-strip (wv&1)*16, bd-half (wv>>1)*32. Denominator via MFMA w/ ones.
// ---------------------------------------------------------------------------
__global__ __launch_bounds__(256) void k_att(const float* __restrict__ dist,
                                             const float* __restrict__ rr,
                                             const _Float16* __restrict__ val_t,
                                             const float* __restrict__ Kvalp,
                                             const float* __restrict__ xminp,
                                             float* __restrict__ out){
    __shared__ alignas(16) _Float16 wtile[32 * 72];   // [i][j]  4.6 KB
    __shared__ alignas(16) _Float16 vtile[64 * 72];   // [bd][j] 9.2 KB

    const int i0 = blockIdx.x * 32;
    const int h  = blockIdx.y;
    const int t  = threadIdx.x;
    const int lane = t & 63, wv = t >> 6;
    const float ts  = head_scale(rr, h);
    const float ts2 = ts * 1.44269504088896f;   // fold log2(e): exp(a)=exp2(a*log2e)

    // staging roles (fixed per thread)
    const int il = t >> 3, jq = t & 7;              // w-stage: row il, 8 j's
    const int vrow = t >> 3, vpart = t & 7;         // v-stage: rows vrow, vrow+32
    const float kvi  = Kvalp[i0 + il];
    const float txmi = ts2 * xminp[i0 + il];
    const float nts2 = -ts2;

    const float* dp = dist + (size_t)(i0 + il) * NN + jq * 8;
    const _Float16* vp0 = val_t + (size_t)(h * BD + vrow) * NN + vpart * 8;
    const _Float16* vp1 = vp0 + (size_t)32 * NN;

    half8 ones;
#pragma unroll
    for (int u = 0; u < 8; u++) ones[u] = (_Float16)1.0f;

    floatx4 acc[2], acc_s;
    acc[0] = (floatx4){0.f,0.f,0.f,0.f};
    acc[1] = (floatx4){0.f,0.f,0.f,0.f};
    acc_s  = (floatx4){0.f,0.f,0.f,0.f};

    const int is16 = (wv & 1) * 16;
    const int bh   = (wv >> 1) * 32;
    const int arow = is16 + (lane & 15);
    const int kq   = (lane >> 4) * 8;

    for (int jt = 0; jt < NN / 64; jt++){
        __syncthreads();   // prev tile consumed

        // v-stage: 2 x (uint4 global -> b128 LDS)
        *(uint4*)&vtile[vrow * 72 + vpart * 8]        = *(const uint4*)vp0;
        *(uint4*)&vtile[(vrow + 32) * 72 + vpart * 8] = *(const uint4*)vp1;
        vp0 += 64; vp1 += 64;

        // w-stage: 8 dist values -> masked exp2 -> f16
        {
            float4 d0 = *(const float4*)dp;
            float4 d1 = *(const float4*)(dp + 4);
            dp += 64;
            float wf[8];
            const float dd[8] = {d0.x,d0.y,d0.z,d0.w,d1.x,d1.y,d1.z,d1.w};
#pragma unroll
            for (int u = 0; u < 8; u++){
                float arg = fmaf(nts2, dd[u], txmi);
                float e = __builtin_amdgcn_exp2f(arg);
                wf[u] = (dd[u] <= kvi) ? e : 0.f;
            }
            half8 hw;
#pragma unroll
            for (int u = 0; u < 8; u++) hw[u] = (_Float16)wf[u];
            *(half8*)&wtile[il * 72 + jq * 8] = hw;
        }
        __syncthreads();

        // MFMA: wave covers 16i x 32bd, K=64 in 2 chunks; + ones-column for S
#pragma unroll
        for (int kc = 0; kc < 2; kc++){
            half8 af = *(half8*)&wtile[arow * 72 + kc * 32 + kq];
            half8 b0 = *(half8*)&vtile[(bh + (lane & 15)) * 72 + kc * 32 + kq];
            half8 b1 = *(half8*)&vtile[(bh + 16 + (lane & 15)) * 72 + kc * 32 + kq];
            acc[0] = __builtin_amdgcn_mfma_f32_16x16x32_f16(af, b0, acc[0], 0, 0, 0);
            acc[1] = __builtin_amdgcn_mfma_f32_16x16x32_f16(af, b1, acc[1], 0, 0, 0);
            acc_s  = __builtin_amdgcn_mfma_f32_16x16x32_f16(af, ones, acc_s, 0, 0, 0);
        }
    }

    // epilogue: D[m][n] m=(lane>>4)*4+reg, n=lane&15; acc_s holds row sums
    const int m0 = (lane >> 4) * 4;
    const int d  = lane & 15;
#pragma unroll
    for (int r4 = 0; r4 < 4; r4++){
        const int iloc = is16 + m0 + r4;
        const float inv_s = 1.0f / fmaxf(acc_s[r4], 1e-30f);
#pragma unroll
        for (int nt = 0; nt < 2; nt++){
            const int b = (wv >> 1) * 2 + nt;
            float c = acc[nt][r4] * inv_s;
            float g = 0.5f * c * (1.0f + erff(c * 0.70710678118654752f));
            out[((size_t)b * NN + i0 + iloc) * (NH * NV) + h * NV + d] = g;
        }
    }
}

// ---------------------------------------------------------------------------
extern "C" void kernel_launch(void* const* d_in, const int* in_sizes, int n_in,
                              void* d_out, int out_size, void* d_ws, size_t ws_size,
                              hipStream_t stream) {
    const float* in   = (const float*)d_in[0]; // (B,N,C) f32
    const float* dist = (const float*)d_in[1]; // (N,N) f32
    const float* r    = (const float*)d_in[2]; // (H,1,1) f32
    const float* wgt  = (const float*)d_in[3]; // (H,C,V) f32
    const int*   loc  = (const int*)d_in[4];   // scalar int
    float* out = (float*)d_out;                // (B,N,H*V) f32

    float* Kval = (float*)d_ws;
    float* xmin = Kval + NN;
    _Float16* val_t = (_Float16*)((char*)d_ws + 2 * (size_t)NN * sizeof(float)); // 4 MB

    k_rowstats<<<NN, 256, 0, stream>>>(dist, loc, Kval, xmin);
    k_value<<<dim3(NN / 16, NH), 256, 0, stream>>>(in, wgt, val_t);
    k_att<<<dim3(NN / 32, NH), 256, 0, stream>>>(dist, r, val_t, Kval, xmin, out);
}

// Round 8
// 186.187 us; speedup vs baseline: 3.7774x; 1.1131x over previous
//
#include <hip/hip_runtime.h>
#include <hip/hip_bf16.h>
#include <math.h>

#define NN 4096
#define NC 128
#define NH 8
#define NV 16
#define NB 4
#define BD 64   // NB*NV

typedef _Float16 half8 __attribute__((ext_vector_type(8)));
typedef float floatx4 __attribute__((ext_vector_type(4)));

__device__ __forceinline__ int get_loc(const int* locp){
    int lr = locp[0];
    return (lr >= 0 && lr <= 100) ? lr : 64;
}
__device__ __forceinline__ float head_scale(const float* rr, int h){
    float ts = tanf(0.78539816339744831f * (1.0f + sinf(rr[h])));
    if (!(ts > 0.f)) ts = (ts == 0.f) ? 1e-20f : 1e20f;
    if (ts > 1e20f) ts = 1e20f;
    return ts;
}
// barrier that drains LDS only — leaves global loads (vmcnt) in flight.
// All cross-wave communication in k_att is via LDS, so lgkmcnt(0)+s_barrier
// is sufficient; "memory" clobber stops compiler reordering across it.
__device__ __forceinline__ void lds_barrier(){
    __asm__ __volatile__("s_waitcnt lgkmcnt(0)\n\ts_barrier" ::: "memory");
}

// ---------------------------------------------------------------------------
// K1: per row i of dist (f32 in [0,1)): Kval_i = rank-th smallest
// (rank = floor(loc*(N-1)/100)+1), xmin_i = row min.  (unchanged from R7)
// ---------------------------------------------------------------------------
__global__ __launch_bounds__(256) void k_rowstats(const float* __restrict__ dist,
                                                  const int* __restrict__ locp,
                                                  float* __restrict__ Kval,
                                                  float* __restrict__ xminp){
    __shared__ unsigned int hist[4][256];
    __shared__ float cand[1024];
    __shared__ unsigned int cnt, selb_s, basec_s, xminu;
    const int i = blockIdx.x, t = threadIdx.x;
    const int wv = t >> 6, lane = t & 63;
    const int loc = get_loc(locp);
    const unsigned int rank = (unsigned int)(((long long)loc * (NN - 1)) / 100) + 1u;

    float v[16];
    const float4* rp = (const float4*)(dist + (size_t)i * NN);
#pragma unroll
    for (int k = 0; k < 4; k++){
        float4 x4 = rp[k * 256 + t];
        v[4*k+0] = x4.x; v[4*k+1] = x4.y; v[4*k+2] = x4.z; v[4*k+3] = x4.w;
    }
    for (int k = t; k < 1024; k += 256) ((unsigned int*)hist)[k] = 0;
    if (t == 0){ cnt = 0; selb_s = 255u; basec_s = 0u; xminu = 0xFFFFFFFFu; }
    __syncthreads();

    float lmin = 1e30f;
#pragma unroll
    for (int u = 0; u < 16; u++){
        float x = v[u];
        lmin = fminf(lmin, x);
        int b = (int)(x * 256.0f); b = b < 0 ? 0 : (b > 255 ? 255 : b);
        atomicAdd(&hist[wv][b], 1u);
    }
#pragma unroll
    for (int off = 1; off < 64; off <<= 1) lmin = fminf(lmin, __shfl_xor(lmin, off));
    if (lane == 0) atomicMin(&xminu, __float_as_uint(lmin));
    __syncthreads();

    if (t < 64){
        unsigned int lp[4];
        unsigned int run = 0;
#pragma unroll
        for (int q = 0; q < 4; q++){
            int b = 4 * t + q;
            run += hist[0][b] + hist[1][b] + hist[2][b] + hist[3][b];
            lp[q] = run;
        }
        unsigned int incl = run;
#pragma unroll
        for (int d = 1; d < 64; d <<= 1){
            unsigned int y = __shfl_up(incl, d);
            if (t >= d) incl += y;
        }
        unsigned int excl = incl - run;
        if (excl < rank && rank <= incl){
#pragma unroll
            for (int q = 0; q < 4; q++){
                if (excl + lp[q] >= rank){
                    selb_s  = (unsigned int)(4 * t + q);
                    basec_s = excl + (q ? lp[q-1] : 0u);
                    break;
                }
            }
        }
    }
    __syncthreads();
    const unsigned int sb = selb_s;
    if (t == 0) Kval[i] = ((float)sb + 1.0f) * 0.00390625f;   // fallback, overwritten below
#pragma unroll
    for (int u = 0; u < 16; u++){
        float x = v[u];
        int b = (int)(x * 256.0f); b = b < 0 ? 0 : (b > 255 ? 255 : b);
        if ((unsigned int)b == sb){
            unsigned int idx = atomicAdd(&cnt, 1u);
            if (idx < 1024u) cand[idx] = x;
        }
    }
    __syncthreads();
    const unsigned int n = cnt > 1024u ? 1024u : cnt;
    const unsigned int need = rank - basec_s;
    for (unsigned int c0 = t; c0 < n; c0 += 256){
        float x = cand[c0];
        unsigned int lt = 0, le = 0;
        for (unsigned int k2 = 0; k2 < n; k2++){
            float y = cand[k2];
            lt += (y < x); le += (y <= x);
        }
        if (lt < need && need <= le) Kval[i] = x;
    }
    if (t == 0) xminp[i] = __uint_as_float(xminu);
}

// ---------------------------------------------------------------------------
// K2: val_t[h][bd][j] = sum_c in[b][j][c] * wgt[h][c][d], bd = b*16+d, f16.
// (unchanged from R6/R7 — passed)
// ---------------------------------------------------------------------------
__global__ __launch_bounds__(256) void k_value(const float* __restrict__ in,
                                               const float* __restrict__ wgt,
                                               _Float16* __restrict__ val_t){
    __shared__ float insh[NC * 65];
    __shared__ float wsh[NC * NV];
    const int j0 = blockIdx.x * 16;
    const int h  = blockIdx.y;
    const int t  = threadIdx.x;

    for (int k = t; k < NC * NV; k += 256) wsh[k] = wgt[h * NC * NV + k];
#pragma unroll
    for (int k = 0; k < 32; k++){
        int idx = k * 256 + t;
        int p = idx >> 7, c = idx & 127;
        int b = p >> 4, jl = p & 15;
        insh[c * 65 + jl * 4 + b] = in[((size_t)b * NN + j0 + jl) * NC + c];
    }
    __syncthreads();

    const int r = t & 63, dq = t >> 6;
    const int jl = r >> 2, b = r & 3;
    float a0 = 0.f, a1 = 0.f, a2 = 0.f, a3 = 0.f;
#pragma unroll 8
    for (int c = 0; c < NC; c++){
        float x = insh[c * 65 + r];
        float4 w4 = *(const float4*)&wsh[c * NV + dq * 4];
        a0 = fmaf(x, w4.x, a0);
        a1 = fmaf(x, w4.y, a1);
        a2 = fmaf(x, w4.z, a2);
        a3 = fmaf(x, w4.w, a3);
    }
    const size_t base = ((size_t)(h * BD + b * NV + dq * 4)) * NN + j0 + jl;
    val_t[base         ] = (_Float16)a0;
    val_t[base + NN    ] = (_Float16)a1;
    val_t[base + 2 * NN] = (_Float16)a2;
    val_t[base + 3 * NN] = (_Float16)a3;
}

// ---------------------------------------------------------------------------
// K3 (MFMA, double-buffered): 32-i tiles, grid (NN/32, NH) = 1024 blocks.
// Per iter: prefetch global (jt+1) -> lds_barrier -> MFMA(jt) -> stage(jt+1).
// One LDS-only barrier per iter; global loads stay in flight across it.
// ---------------------------------------------------------------------------
__global__ __launch_bounds__(256) void k_att(const float* __restrict__ dist,
                                             const float* __restrict__ rr,
                                             const _Float16* __restrict__ val_t,
                                             const float* __restrict__ Kvalp,
                                             const float* __restrict__ xminp,
                                             float* __restrict__ out){
    __shared__ alignas(16) _Float16 wtile[2][32 * 72];   // [i][j]  2 x 4.6 KB
    __shared__ alignas(16) _Float16 vtile[2][64 * 72];   // [bd][j] 2 x 9.2 KB

    const int i0 = blockIdx.x * 32;
    const int h  = blockIdx.y;
    const int t  = threadIdx.x;
    const int lane = t & 63, wv = t >> 6;
    const float ts  = head_scale(rr, h);
    const float ts2 = ts * 1.44269504088896f;   // exp(a) = exp2(a*log2e)

    // staging roles (fixed per thread)
    const int il = t >> 3, jq = t & 7;          // w-stage: row il, 8 j's
    const int vrow = t >> 3, vpart = t & 7;     // v-stage: rows vrow, vrow+32
    const float kvi  = Kvalp[i0 + il];
    const float txmi = ts2 * xminp[i0 + il];
    const float nts2 = -ts2;

    const float* dp = dist + (size_t)(i0 + il) * NN + jq * 8;
    const _Float16* vp0 = val_t + (size_t)(h * BD + vrow) * NN + vpart * 8;
    const _Float16* vp1 = vp0 + (size_t)32 * NN;

    half8 ones;
#pragma unroll
    for (int u = 0; u < 8; u++) ones[u] = (_Float16)1.0f;

    floatx4 acc0 = (floatx4){0.f,0.f,0.f,0.f};
    floatx4 acc1 = (floatx4){0.f,0.f,0.f,0.f};
    floatx4 accs = (floatx4){0.f,0.f,0.f,0.f};

    const int is16 = (wv & 1) * 16;
    const int bh   = (wv >> 1) * 32;
    const int aoff  = (is16 + (lane & 15)) * 72 + (lane >> 4) * 8;
    const int boff0 = (bh + (lane & 15)) * 72 + (lane >> 4) * 8;
    const int boff1 = boff0 + 16 * 72;
    const int voff0 = vrow * 72 + vpart * 8;
    const int voff1 = (vrow + 32) * 72 + vpart * 8;
    const int woff  = il * 72 + jq * 8;

    // ---- prologue: load + stage tile 0 into buffer 0
    uint4 pv0 = *(const uint4*)vp0;  vp0 += 64;
    uint4 pv1 = *(const uint4*)vp1;  vp1 += 64;
    float4 pd0 = *(const float4*)dp;
    float4 pd1 = *(const float4*)(dp + 4);  dp += 64;

    {
        *(uint4*)&vtile[0][voff0] = pv0;
        *(uint4*)&vtile[0][voff1] = pv1;
        const float dd[8] = {pd0.x,pd0.y,pd0.z,pd0.w,pd1.x,pd1.y,pd1.z,pd1.w};
        half8 hw;
#pragma unroll
        for (int u = 0; u < 8; u++){
            float e = __builtin_amdgcn_exp2f(fmaf(nts2, dd[u], txmi));
            hw[u] = (_Float16)((dd[u] <= kvi) ? e : 0.f);
        }
        *(half8*)&wtile[0][woff] = hw;
    }

    for (int jt = 0; jt < NN / 64; jt++){
        const int cur = jt & 1;
        const bool more = (jt != NN / 64 - 1);
        if (more){
            pv0 = *(const uint4*)vp0;  vp0 += 64;
            pv1 = *(const uint4*)vp1;  vp1 += 64;
            pd0 = *(const float4*)dp;
            pd1 = *(const float4*)(dp + 4);  dp += 64;
        }
        lds_barrier();   // publishes buf[cur]; buf[1-cur] free; vmcnt stays in flight

        // MFMA on buf[cur]: 16i x 32bd per wave, K=64 in 2 chunks + ones for S
#pragma unroll
        for (int kc = 0; kc < 2; kc++){
            half8 af = *(const half8*)&wtile[cur][aoff + kc * 32];
            half8 b0 = *(const half8*)&vtile[cur][boff0 + kc * 32];
            half8 b1 = *(const half8*)&vtile[cur][boff1 + kc * 32];
            acc0 = __builtin_amdgcn_mfma_f32_16x16x32_f16(af, b0, acc0, 0, 0, 0);
            acc1 = __builtin_amdgcn_mfma_f32_16x16x32_f16(af, b1, acc1, 0, 0, 0);
            accs = __builtin_amdgcn_mfma_f32_16x16x32_f16(af, ones, accs, 0, 0, 0);
        }

        if (more){
            const int nxt = 1 - cur;
            *(uint4*)&vtile[nxt][voff0] = pv0;
            *(uint4*)&vtile[nxt][voff1] = pv1;
            const float dd[8] = {pd0.x,pd0.y,pd0.z,pd0.w,pd1.x,pd1.y,pd1.z,pd1.w};
            half8 hw;
#pragma unroll
            for (int u = 0; u < 8; u++){
                float e = __builtin_amdgcn_exp2f(fmaf(nts2, dd[u], txmi));
                hw[u] = (_Float16)((dd[u] <= kvi) ? e : 0.f);
            }
            *(half8*)&wtile[nxt][woff] = hw;
        }
    }

    // epilogue: D[m][n]: m=(lane>>4)*4+reg, n=lane&15; accs holds row-sums S
    const int m0 = (lane >> 4) * 4;
    const int d  = lane & 15;
#pragma unroll
    for (int r4 = 0; r4 < 4; r4++){
        const int iloc = is16 + m0 + r4;
        const float inv_s = 1.0f / fmaxf(accs[r4], 1e-30f);
#pragma unroll
        for (int nt = 0; nt < 2; nt++){
            const int b = (wv >> 1) * 2 + nt;
            float c = acc0[r4], c1 = acc1[r4];
            float cc = (nt == 0 ? c : c1) * inv_s;
            float g = 0.5f * cc * (1.0f + erff(cc * 0.70710678118654752f));
            out[((size_t)b * NN + i0 + iloc) * (NH * NV) + h * NV + d] = g;
        }
    }
}

// ---------------------------------------------------------------------------
extern "C" void kernel_launch(void* const* d_in, const int* in_sizes, int n_in,
                              void* d_out, int out_size, void* d_ws, size_t ws_size,
                              hipStream_t stream) {
    const float* in   = (const float*)d_in[0]; // (B,N,C) f32
    const float* dist = (const float*)d_in[1]; // (N,N) f32
    const float* r    = (const float*)d_in[2]; // (H,1,1) f32
    const float* wgt  = (const float*)d_in[3]; // (H,C,V) f32
    const int*   loc  = (const int*)d_in[4];   // scalar int
    float* out = (float*)d_out;                // (B,N,H*V) f32

    float* Kval = (float*)d_ws;
    float* xmin = Kval + NN;
    _Float16* val_t = (_Float16*)((char*)d_ws + 2 * (size_t)NN * sizeof(float)); // 4 MB

    k_rowstats<<<NN, 256, 0, stream>>>(dist, loc, Kval, xmin);
    k_value<<<dim3(NN / 16, NH), 256, 0, stream>>>(in, wgt, val_t);
    k_att<<<dim3(NN / 32, NH), 256, 0, stream>>>(dist, r, val_t, Kval, xmin, out);
}